// Round 6
// baseline (84.221 us; speedup 1.0000x reference)
//
#include <hip/hip_runtime.h>

// OverlapCalculator: pairwise IoU [50000 x 2000] fp32, row max + argmax.
// Outputs (flat fp32): pred_bbox[200000] | gt_bbox[8000] | max[50000] | argmax-as-float[50000]
//
// SINGLE-DISPATCH fused kernel. Each block redundantly builds the 2D cell
// index (32x16 bins over g.x/g.y) from the raw gts straight into its own LDS,
// then scans its 128 preds' windows. No workspace use, no second launch.
//
// Bit-exactness (vs numpy fp32):
//  - q > 0 requires x-overlap AND y-overlap; any gt outside the window has
//    w == 0 or h == 0 EXACTLY -> q = 0/un = 0 exactly -> cannot affect the
//    row max. All-zero rows: iou[0] == 0 -> ref argmax = 0 = our init (0,0).
//  - Survivors get the EXACT ref expression (contract off, IEEE divide).
//  - Lexicographic (q, smallest-orig-idx) running max + reduce is
//    scan-order-independent => per-cell atomic permutation and block
//    redundancy are harmless; all blocks compute identical bin params
//    (deterministic same-order reductions on identical input).
//  - in > 0 guard only skips q == 0 exactly -> harmless.
//
// Window-inclusion proof sketch: binning b(v)=clamp(floor((v-min)*inv)) is
// monotone (fp mul/floor monotone). g.z > p.x => g.x > p.x-(g.z-g.x) >=
// p.x-mgw-1e-5 > fl(p.x-mgw-0.5f) => xbin(g.x) >= bl; g.x < p.z =>
// xbin(g.x) <= bh. Same in y with mgh. 0.5 abs slack covers all fp rounding
// of the bound exprs (coords <= ~1100).

#define N_PRED 50000
#define N_GT   2000
#define NXB    32
#define NYB    16
#define NCELL  (NXB * NYB)     // 512
#define BLOCK  256
#define LPP    8               // lanes cooperating on one pred
#define NGRP   (BLOCK / LPP)   // 32 lane-groups per block
#define PPT    4               // preds per lane-group (sequential)
#define PPB    (NGRP * PPT)    // 128 preds per block

__device__ __forceinline__ int bin1(float v, float mn, float inv, int nb) {
    int b = (int)floorf((v - mn) * inv);
    return max(0, min(nb - 1, b));
}

__global__ __launch_bounds__(BLOCK) void iou_fused(
        const float4* __restrict__ pred, const float4* __restrict__ gt,
        float* __restrict__ out) {
#pragma clang fp contract(off)
    __shared__ float4         sgt[N_GT];    // 32 KB  sorted gts
    __shared__ unsigned short sidx[N_GT];   //  4 KB  orig indices
    __shared__ int            cur[NCELL];   //  2 KB  hist -> excl -> incl
    __shared__ float          wred[4][6];
    __shared__ int            wsum[4];
    __shared__ float          s_par[6];

    const int tid  = threadIdx.x;
    const int lane = tid & 63;
    const int wv   = tid >> 6;              // 4 waves

    cur[tid] = 0; cur[tid + BLOCK] = 0;     // zero 512-cell histogram

    // --- pass 1: min/max/extent reduce (+ gt passthrough from block 0) ------
    float xm = 3.4e38f, xM = -3.4e38f, ym = 3.4e38f, yM = -3.4e38f;
    float w = 0.0f, h = 0.0f;
    for (int j = tid; j < N_GT; j += BLOCK) {
        const float4 g = gt[j];
        xm = fminf(xm, g.x); xM = fmaxf(xM, g.x);
        ym = fminf(ym, g.y); yM = fmaxf(yM, g.y);
        w  = fmaxf(w, g.z - g.x);
        h  = fmaxf(h, g.w - g.y);
        if (blockIdx.x == 0) ((float4*)(out + 4 * N_PRED))[j] = g;
    }
#pragma unroll
    for (int s = 1; s < 64; s <<= 1) {
        xm = fminf(xm, __shfl_xor(xm, s));
        xM = fmaxf(xM, __shfl_xor(xM, s));
        ym = fminf(ym, __shfl_xor(ym, s));
        yM = fmaxf(yM, __shfl_xor(yM, s));
        w  = fmaxf(w,  __shfl_xor(w,  s));
        h  = fmaxf(h,  __shfl_xor(h,  s));
    }
    if (lane == 0) {
        wred[wv][0] = xm; wred[wv][1] = xM; wred[wv][2] = ym;
        wred[wv][3] = yM; wred[wv][4] = w;  wred[wv][5] = h;
    }
    __syncthreads();                                            // B1
    if (tid == 0) {
        float a0 = wred[0][0], a1 = wred[0][1], a2 = wred[0][2];
        float a3 = wred[0][3], a4 = wred[0][4], a5 = wred[0][5];
        for (int k = 1; k < 4; ++k) {
            a0 = fminf(a0, wred[k][0]); a1 = fmaxf(a1, wred[k][1]);
            a2 = fminf(a2, wred[k][2]); a3 = fmaxf(a3, wred[k][3]);
            a4 = fmaxf(a4, wred[k][4]); a5 = fmaxf(a5, wred[k][5]);
        }
        s_par[0] = a0;
        s_par[1] = (float)NXB / fmaxf(a1 - a0, 1e-20f);
        s_par[2] = a2;
        s_par[3] = (float)NYB / fmaxf(a3 - a2, 1e-20f);
        s_par[4] = a4;
        s_par[5] = a5;
    }
    __syncthreads();                                            // B2
    const float xmin = s_par[0], invx = s_par[1];
    const float ymin = s_par[2], invy = s_par[3];
    const float mgw  = s_par[4], mgh  = s_par[5];

    // --- pass 2: histogram ---------------------------------------------------
    for (int j = tid; j < N_GT; j += BLOCK) {
        const float4 g = gt[j];                  // L1-hot re-read
        const int c = bin1(g.x, xmin, invx, NXB) * NYB +
                      bin1(g.y, ymin, invy, NYB);
        atomicAdd(&cur[c], 1);
    }
    __syncthreads();                                            // B3

    // --- exclusive scan of 512 cells (thread owns pair 2t,2t+1) -------------
    const int a0 = cur[2 * tid], a1 = cur[2 * tid + 1];
    const int ps = a0 + a1;
    int x = ps;
#pragma unroll
    for (int s = 1; s < 64; s <<= 1) {
        const int t = __shfl_up(x, s);
        if (lane >= s) x += t;
    }
    if (lane == 63) wsum[wv] = x;
    __syncthreads();                                            // B4
    if (tid == 0) {
        int acc = 0;
        for (int k = 0; k < 4; ++k) { const int t = wsum[k]; wsum[k] = acc; acc += t; }
    }
    __syncthreads();                                            // B5
    const int base = wsum[wv] + (x - ps);       // exclusive prefix of pair
    cur[2 * tid]     = base;
    cur[2 * tid + 1] = base + a0;
    __syncthreads();                                            // B6

    // --- pass 3: scatter into sorted LDS table ------------------------------
    for (int j = tid; j < N_GT; j += BLOCK) {
        const float4 g = gt[j];
        const int c = bin1(g.x, xmin, invx, NXB) * NYB +
                      bin1(g.y, ymin, invy, NYB);
        const int pos = atomicAdd(&cur[c], 1);
        sgt[pos]  = g;
        sidx[pos] = (unsigned short)j;
    }
    __syncthreads();                                            // B7
    // now cur[c] == inclusive count => excl(c) = (c ? cur[c-1] : 0)

    // --- window scan: 8 lanes per pred, 4 preds per group --------------------
    const int grp = (int)(threadIdx.x >> 3);    // 0..31
    const int sub = threadIdx.x & (LPP - 1);

#pragma unroll
    for (int k = 0; k < PPT; ++k) {
        const int  pid = blockIdx.x * PPB + k * NGRP + grp;
        const bool act = pid < N_PRED;
        const float4 p  = pred[act ? pid : 0];
        const float  ap = (p.z - p.x) * (p.w - p.y);

        int bl = 0, bh = -1, yl = 0, yh1 = 1;
        if (act) {
            bl  = bin1(p.x - mgw - 0.5f, xmin, invx, NXB);
            bh  = bin1(p.z,              xmin, invx, NXB);
            yl  = bin1(p.y - mgh - 0.5f, ymin, invy, NYB);
            yh1 = bin1(p.w,              ymin, invy, NYB) + 1;
        }

        float best = 0.0f;   // row max >= 0; (0,0) matches all-zero rows
        int   bidx = 0;
        for (int b = bl; b <= bh; ++b) {
            const int c0  = b * NYB + yl;
            const int rlo = c0 ? cur[c0 - 1] : 0;
            const int rhi = cur[b * NYB + yh1 - 1];
            for (int t = rlo + sub; t < rhi; t += LPP) {
                const float4 g  = sgt[t];
                const int    oi = sidx[t];
                const float  ag = (g.z - g.x) * (g.w - g.y); // same fl expr as ref
                const float  w2 = fmaxf(fminf(p.z, g.z) - fmaxf(p.x, g.x), 0.0f);
                const float  h2 = fmaxf(fminf(p.w, g.w) - fmaxf(p.y, g.y), 0.0f);
                const float  in = w2 * h2;
                if (in > 0.0f) {                 // in==0 -> q==0 exactly: skip
                    const float un = (ap + ag) - in;         // ref assoc order
                    const float q  = in / un;                // exact IEEE divide
                    if (q > best || (q == best && oi < bidx)) { best = q; bidx = oi; }
                }
            }
        }
        // lexicographic (q, -idx) reduce across the 8-lane group
#pragma unroll
        for (int s = 1; s < LPP; s <<= 1) {
            const float oq = __shfl_xor(best, s);
            const int   oi = __shfl_xor(bidx, s);
            if (oq > best || (oq == best && oi < bidx)) { best = oq; bidx = oi; }
        }
        if (act && sub == 0) {
            ((float4*)out)[pid] = p;                         // pred passthrough
            out[4 * N_PRED + 4 * N_GT + pid]          = best;
            out[4 * N_PRED + 4 * N_GT + N_PRED + pid] = (float)bidx;
        }
    }
}

extern "C" void kernel_launch(void* const* d_in, const int* in_sizes, int n_in,
                              void* d_out, int out_size, void* d_ws, size_t ws_size,
                              hipStream_t stream) {
    const float4* pred = (const float4*)d_in[0];
    const float4* gt   = (const float4*)d_in[1];
    float* out = (float*)d_out;
    (void)d_ws; (void)ws_size;                    // workspace unused

    const int gx = (N_PRED + PPB - 1) / PPB;      // 391
    iou_fused<<<gx, BLOCK, 0, stream>>>(pred, gt, out);
}

// Round 7
// 77.374 us; speedup vs baseline: 1.0885x; 1.0885x over previous
//
#include <hip/hip_runtime.h>

// OverlapCalculator: pairwise IoU [50000 x 2000] fp32, row max + argmax.
// Outputs (flat fp32): pred_bbox[200000] | gt_bbox[8000] | max[50000] | argmax-as-float[50000]
//
// 2D spatially-pruned, bit-exact vs numpy fp32:
//  q > 0 requires x-overlap (g.x < p.z and g.z > p.x) AND y-overlap
//  (g.y < p.w and g.w > p.y). Any gt failing either has w == 0 or h == 0
//  EXACTLY -> q = 0/un = 0 exactly, so skipping it cannot change the row max;
//  all-zero rows have iou[0] == 0 -> ref argmax = 0, matched by init (0,0).
//  Surviving candidates get the EXACT reference fp expression (contract off,
//  IEEE divide) + lexicographic (q, -orig_idx) reduce => bit-exact max and
//  numpy first-occurrence argmax.  The in > 0 divide guard only skips
//  candidates whose q == 0 exactly (in == 0) -> harmless.
//
//  build_index (1 block x 512, wave-shfl reductions/scans, ~5 barriers):
//    counting-sort gts into 32x16 (xbin,ybin) cells, compute xmin/ymin,
//    inv bin widths, max gt width/height; write sorted gt + orig idx +
//    cell starts to ws; gt passthrough. Each thread caches its <=4 gts in
//    registers across all phases.
//  iou_max (391 blocks x 512): stage sorted table in LDS (~39 KB), 8 lanes
//    per pred, 2 preds sequentially per lane-group -> 128 preds/block
//    (LDS reuse 4.8x, single scheduling round). Window scan over ~6
//    contiguous runs (~75 of 2000 gts), shfl_xor lex-reduce; pred
//    passthrough.
//
//  Window-inclusion proof sketch (bit-level): binning b(v) = clamp(floor(
//  (v-min)*inv)) is monotone in v (fp mul/floor are monotone). If g.z > p.x
//  then g.x > p.x - (g.z-g.x) >= p.x - mgw - 1e-5 (mgw = max fl(g.z-g.x),
//  values <= 1100 so fl error of the bound expr < 1e-4) > fl(p.x-mgw-0.5f)
//  -> xbin(g.x) >= bl. g.x < p.z -> xbin(g.x) <= bh. Same in y.

#define N_PRED 50000
#define N_GT   2000
#define NXB    32
#define NYB    16
#define NCELL  (NXB * NYB)     // 512
#define BLOCK  512
#define LPP    8               // lanes cooperating on one pred
#define NGRP   (BLOCK / LPP)   // 64 lane-groups per block
#define PPT    2               // preds per lane-group (sequential)
#define PPB    (NGRP * PPT)    // 128 preds per block

__device__ __forceinline__ int bin1(float v, float mn, float inv, int nb) {
    int b = (int)floorf((v - mn) * inv);
    return max(0, min(nb - 1, b));
}

// --- setup: counting-sort 2000 gts into 512 (x,y) cells; 1 block x 512 ------
__global__ __launch_bounds__(512) void build_index(
        const float4* __restrict__ gt,
        float4* __restrict__ ws_gt, unsigned short* __restrict__ ws_idx,
        int* __restrict__ ws_cell, float* __restrict__ ws_par,
        float* __restrict__ out) {
#pragma clang fp contract(off)
    __shared__ float wred[8][6];
    __shared__ int   wsum[8];
    __shared__ float s_par[6];
    __shared__ int   hist[NCELL];    // doubles as cursor after scan
    const int tid  = threadIdx.x;
    const int lane = tid & 63;
    const int wv   = tid >> 6;       // 8 waves

    hist[tid] = 0;                   // NCELL == blockDim == 512

    // load + cache this thread's gts (<=4), partial min/max, gt passthrough
    float4 gr[4];
    int    nloc = 0;
    float xm = 3.4e38f, xM = -3.4e38f, ym = 3.4e38f, yM = -3.4e38f;
    float w = 0.0f, h = 0.0f;
    for (int j = tid; j < N_GT; j += 512) {
        const float4 g = gt[j];
        gr[nloc++] = g;
        xm = fminf(xm, g.x); xM = fmaxf(xM, g.x);
        ym = fminf(ym, g.y); yM = fmaxf(yM, g.y);
        w  = fmaxf(w, g.z - g.x);
        h  = fmaxf(h, g.w - g.y);
        ((float4*)(out + 4 * N_PRED))[j] = g;    // gt passthrough
    }
    // wave-level butterfly reductions (no barriers)
#pragma unroll
    for (int s = 1; s < 64; s <<= 1) {
        xm = fminf(xm, __shfl_xor(xm, s));
        xM = fmaxf(xM, __shfl_xor(xM, s));
        ym = fminf(ym, __shfl_xor(ym, s));
        yM = fmaxf(yM, __shfl_xor(yM, s));
        w  = fmaxf(w,  __shfl_xor(w,  s));
        h  = fmaxf(h,  __shfl_xor(h,  s));
    }
    if (lane == 0) {
        wred[wv][0] = xm; wred[wv][1] = xM; wred[wv][2] = ym;
        wred[wv][3] = yM; wred[wv][4] = w;  wred[wv][5] = h;
    }
    __syncthreads();                                            // B1
    if (tid == 0) {
        float a0 = wred[0][0], a1 = wred[0][1], a2 = wred[0][2];
        float a3 = wred[0][3], a4 = wred[0][4], a5 = wred[0][5];
        for (int k = 1; k < 8; ++k) {
            a0 = fminf(a0, wred[k][0]); a1 = fmaxf(a1, wred[k][1]);
            a2 = fminf(a2, wred[k][2]); a3 = fmaxf(a3, wred[k][3]);
            a4 = fmaxf(a4, wred[k][4]); a5 = fmaxf(a5, wred[k][5]);
        }
        s_par[0] = a0;
        s_par[1] = (float)NXB / fmaxf(a1 - a0, 1e-20f);
        s_par[2] = a2;
        s_par[3] = (float)NYB / fmaxf(a3 - a2, 1e-20f);
        s_par[4] = a4;
        s_par[5] = a5;
        for (int k = 0; k < 6; ++k) ws_par[k] = s_par[k];
    }
    __syncthreads();                                            // B2
    const float xmin = s_par[0], invx = s_par[1];
    const float ymin = s_par[2], invy = s_par[3];

    int cellr[4];
    for (int i = 0; i < nloc; ++i) {
        cellr[i] = bin1(gr[i].x, xmin, invx, NXB) * NYB +
                   bin1(gr[i].y, ymin, invy, NYB);
        atomicAdd(&hist[cellr[i]], 1);
    }
    __syncthreads();                                            // B3

    // two-level inclusive scan over NCELL == 512 (wave shfl + 8 wave sums)
    const int v = hist[tid];
    int x = v;
#pragma unroll
    for (int s = 1; s < 64; s <<= 1) {
        const int t = __shfl_up(x, s);
        if (lane >= s) x += t;
    }
    if (lane == 63) wsum[wv] = x;
    __syncthreads();                                            // B4
    if (wv == 0) {
        int t = (lane < 8) ? wsum[lane] : 0;
#pragma unroll
        for (int s = 1; s < 8; s <<= 1) {
            const int u = __shfl_up(t, s);
            if (lane >= s) t += u;
        }
        if (lane < 8) wsum[lane] = t;
    }
    __syncthreads();                                            // B5
    const int incl = x + (wv ? wsum[wv - 1] : 0);
    const int excl = incl - v;
    ws_cell[tid] = excl;
    if (tid == NCELL - 1) ws_cell[NCELL] = incl;                // == N_GT
    hist[tid] = excl;                                           // -> cursor
    __syncthreads();                                            // B6

    for (int i = 0; i < nloc; ++i) {
        const int pos = atomicAdd(&hist[cellr[i]], 1);
        ws_gt[pos]  = gr[i];
        ws_idx[pos] = (unsigned short)(tid + i * 512);
    }
}

// --- main: 8 lanes per pred, 2 preds per group, table in LDS ----------------
__global__ __launch_bounds__(BLOCK) void iou_max(
        const float4* __restrict__ pred,
        const float4* __restrict__ ws_gt, const unsigned short* __restrict__ ws_idx,
        const int* __restrict__ ws_cell, const float* __restrict__ ws_par,
        float* __restrict__ out) {
#pragma clang fp contract(off)
    __shared__ float4         sgt[N_GT];        // 32 KB
    __shared__ unsigned short sidx[N_GT];       //  4 KB
    __shared__ int            scell[NCELL + 1]; //  2 KB

    for (int j = threadIdx.x; j < N_GT; j += BLOCK) {
        sgt[j]  = ws_gt[j];
        sidx[j] = ws_idx[j];
    }
    for (int j = threadIdx.x; j < NCELL + 1; j += BLOCK) scell[j] = ws_cell[j];
    const float xmin = ws_par[0], invx = ws_par[1];
    const float ymin = ws_par[2], invy = ws_par[3];
    const float mgw  = ws_par[4], mgh  = ws_par[5];
    __syncthreads();

    const int grp = (int)(threadIdx.x >> 3);        // 0..63
    const int sub = threadIdx.x & (LPP - 1);

#pragma unroll
    for (int k = 0; k < PPT; ++k) {
        const int  pid = blockIdx.x * PPB + k * NGRP + grp;
        const bool act = pid < N_PRED;
        const float4 p  = pred[act ? pid : 0];
        const float  ap = (p.z - p.x) * (p.w - p.y);

        int bl = 0, bh = -1, yl = 0, yh1 = 0;
        if (act) {
            // 0.5 abs slack covers fp rounding of mgw/mgh and the bound expr;
            // any over-included gt evaluates to q == 0 exactly -> harmless.
            bl  = bin1(p.x - mgw - 0.5f, xmin, invx, NXB);
            bh  = bin1(p.z,              xmin, invx, NXB);
            yl  = bin1(p.y - mgh - 0.5f, ymin, invy, NYB);
            yh1 = bin1(p.w,              ymin, invy, NYB) + 1;
        }

        float best = 0.0f;   // row max >= 0; (0,0) matches all-zero rows
        int   bidx = 0;
        for (int b = bl; b <= bh; ++b) {
            const int rlo = scell[b * NYB + yl];
            const int rhi = scell[b * NYB + yh1];
            for (int t = rlo + sub; t < rhi; t += LPP) {
                const float4 g  = sgt[t];
                const int    oi = sidx[t];
                const float  ag = (g.z - g.x) * (g.w - g.y); // same fl expr as ref
                const float  w  = fmaxf(fminf(p.z, g.z) - fmaxf(p.x, g.x), 0.0f);
                const float  h  = fmaxf(fminf(p.w, g.w) - fmaxf(p.y, g.y), 0.0f);
                const float  in = w * h;
                if (in > 0.0f) {                 // in==0 -> q==0 exactly: skip
                    const float un = (ap + ag) - in;         // ref assoc order
                    const float q  = in / un;                // exact IEEE divide
                    if (q > best || (q == best && oi < bidx)) { best = q; bidx = oi; }
                }
            }
        }
        // lexicographic (q, -idx) reduce across the 8-lane group
#pragma unroll
        for (int s = 1; s < LPP; s <<= 1) {
            const float oq = __shfl_xor(best, s);
            const int   oi = __shfl_xor(bidx, s);
            if (oq > best || (oq == best && oi < bidx)) { best = oq; bidx = oi; }
        }
        if (act && sub == 0) {
            ((float4*)out)[pid] = p;                         // pred passthrough
            out[4 * N_PRED + 4 * N_GT + pid]          = best;
            out[4 * N_PRED + 4 * N_GT + N_PRED + pid] = (float)bidx;
        }
    }
}

extern "C" void kernel_launch(void* const* d_in, const int* in_sizes, int n_in,
                              void* d_out, int out_size, void* d_ws, size_t ws_size,
                              hipStream_t stream) {
    const float4* pred = (const float4*)d_in[0];
    const float4* gt   = (const float4*)d_in[1];
    float* out = (float*)d_out;

    char* ws = (char*)d_ws;                       // ~39 KB used
    float4*         ws_gt   = (float4*)ws;                         // 32768 B
    unsigned short* ws_idx  = (unsigned short*)(ws + 32768);       //  4096 B
    int*            ws_cell = (int*)(ws + 32768 + 4096);           //  2304 B
    float*          ws_par  = (float*)(ws + 32768 + 4096 + 2304);

    build_index<<<1, 512, 0, stream>>>(gt, ws_gt, ws_idx, ws_cell, ws_par, out);

    const int gx = (N_PRED + PPB - 1) / PPB;      // 391
    iou_max<<<gx, BLOCK, 0, stream>>>(pred, ws_gt, ws_idx, ws_cell, ws_par, out);
}